// Round 16
// baseline (246.103 us; speedup 1.0000x reference)
//
#include <hip/hip_runtime.h>

// (B,T,E,H,HS) = (8,1024,1024,16,64). Inputs/output: float32 (proven r6-r12).
// Internals bf16 MFMA. r14 = BK=64 XOR-swizzled GEMM (conflicts 6.29M -> 0).
// r19 = hoisted staging pointers. r28 = r19 restored byte-exact = SESSION
// BEST (245.9us). Ledger: 2-phase GEMM NULL (r21); swapped-QK^T K=16 PV
// -5us (r22 vs r28); async-dbuf line net-negative (r23-r26); ones-MFMA -10us
// on v8-structure (r27). r29 = r28 + XCD swizzle on attn ONLY (the one
// r24-proven lever never applied to the winning v8 body): grid (px,bh)
// linearization put the 8 px-siblings sharing one bh's K/V on 8 different
// XCDs (r23 counters: FETCH 110.7MB vs ~32MB compulsory); 1-D id decode
// bh=(id&7)|((id>>6)<<3), px=(id>>3)&7 keeps siblings on one XCD's L2.
// Body of attn_v8 byte-identical otherwise.
#define B_  8
#define T_  1024
#define E_  1024
#define H_  16
#define HS_ 64
#define K_  1024

typedef __bf16 bf16x8 __attribute__((ext_vector_type(8)));
typedef float  f32x4  __attribute__((ext_vector_type(4)));
typedef unsigned short us;

__device__ __forceinline__ us f2bf(float f) {           // RNE
    union { float f; unsigned int i; } c; c.f = f;
    unsigned int x = c.i;
    return (us)((x + 0x7fff + ((x >> 16) & 1)) >> 16);
}
__device__ __forceinline__ us f2bf_t(float f) {         // truncate (P only)
    union { float f; unsigned int i; } c; c.f = f;
    return (us)(c.i >> 16);
}
__device__ __forceinline__ bf16x8 cvt8(const float* p) {
    float4 a = *reinterpret_cast<const float4*>(p);
    float4 b = *reinterpret_cast<const float4*>(p + 4);
    union { bf16x8 v; us u[8]; } c;
    c.u[0] = f2bf(a.x); c.u[1] = f2bf(a.y); c.u[2] = f2bf(a.z); c.u[3] = f2bf(a.w);
    c.u[4] = f2bf(b.x); c.u[5] = f2bf(b.y); c.u[6] = f2bf(b.z); c.u[7] = f2bf(b.w);
    return c.v;
}
// Async global->LDS 16B/lane; LDS dest = wave-uniform base + lane*16 (m97/m104).
__device__ __forceinline__ void async_cp16(const us* g, us* l) {
    __builtin_amdgcn_global_load_lds((const unsigned int*)g, (unsigned int*)l, 16, 0, 0);
}

// ---------------------------------------------------------------------------
// One-shot f32 -> bf16 conversion of x and the four weight matrices.
// ---------------------------------------------------------------------------
__global__ __launch_bounds__(256) void cvt_kernel(
    const float* __restrict__ sx, const float* __restrict__ sq,
    const float* __restrict__ sk, const float* __restrict__ sv,
    const float* __restrict__ sp,
    us* __restrict__ dx, us* __restrict__ dq, us* __restrict__ dk,
    us* __restrict__ dv, us* __restrict__ dp)
{
    const int y = blockIdx.y;
    const float* src = (y == 0) ? sx : (y == 1) ? sq : (y == 2) ? sk : (y == 3) ? sv : sp;
    us*          dst = (y == 0) ? dx : (y == 1) ? dq : (y == 2) ? dk : (y == 3) ? dv : dp;
    const size_t n = (y == 0) ? (size_t)B_ * T_ * E_ : (size_t)E_ * E_;
    const size_t i = ((size_t)blockIdx.x * 256 + threadIdx.x) * 8;
    if (i >= n) return;
    *reinterpret_cast<bf16x8*>(dst + i) = cvt8(src + i);
}

// ---------------------------------------------------------------------------
// 128x128 all-bf16 GEMM, BK=64, global_load_lds width-16 staging, XOR-swizzled
// LDS (conflict-free, r14), hoisted pointers (r19). 1-phase: 2-phase proven
// NULL here (r21 == r19; m99/m100). Do NOT grow the tile (r10: 216 VGPR
// collapse) or force min-waves bounds (r11: spill).
// ---------------------------------------------------------------------------
__global__ __launch_bounds__(256) void qkv_gf(
    const us* __restrict__ A,
    const us* __restrict__ Wq, const us* __restrict__ Wk, const us* __restrict__ Wv,
    us* __restrict__ q, us* __restrict__ k, us* __restrict__ vT)
{
    const int type = blockIdx.z;
    const us* Bm = (type == 0) ? Wq : (type == 1) ? Wk : Wv;
    us* out      = (type == 0) ? q  : (type == 1) ? k  : vT;
    const int vtrans = (type == 2);

    __shared__ __align__(16) us As[128 * 64];
    __shared__ __align__(16) us Bs[128 * 64];

    const int tid  = threadIdx.x;
    const int lane = tid & 63;
    const int w    = tid >> 6;
    const int quad = lane >> 4;
    const int l15  = lane & 15;
    const int wm   = w >> 1, wn = w & 1;
    const int row0 = blockIdx.x * 128;
    const int col0 = blockIdx.y * 128;
    const int x7   = l15 & 7;          // fragment row & 7 (rows are +multiple of 8)
    const int ca0  = (quad ^ x7) * 8;          // swizzled read chunk, kk=0
    const int ca1  = ((4 + quad) ^ x7) * 8;    // kk=1

    // hoisted staging pointers: advance 64 elems (128B) per K-step
    const us* pa[4]; const us* pb[4];
#pragma unroll
    for (int i = 0; i < 4; ++i) {
        const int idx = tid + i * 256;          // 0..1023
        const int r   = idx >> 3;               // tile row 0..127
        const int c8  = ((idx & 7) ^ (r & 7)) * 8;  // inverse-swizzled src chunk
        pa[i] = A  + (size_t)(row0 + r) * K_ + c8;
        pb[i] = Bm + (size_t)(col0 + r) * K_ + c8;
    }

    f32x4 acc[4][4] = {};
    for (int k0 = 0; k0 < K_; k0 += 64) {
        __syncthreads();
#pragma unroll
        for (int i = 0; i < 4; ++i) {
            async_cp16(pa[i], &As[(tid + i * 256) * 8]);
            async_cp16(pb[i], &Bs[(tid + i * 256) * 8]);
            pa[i] += 64; pb[i] += 64;
        }
        __syncthreads();
#pragma unroll
        for (int kk = 0; kk < 2; ++kk) {
            const int ca = kk ? ca1 : ca0;
            bf16x8 af[4], bf[4];
#pragma unroll
            for (int t = 0; t < 4; ++t) {
                af[t] = *reinterpret_cast<const bf16x8*>(&As[(wm * 64 + t * 16 + l15) * 64 + ca]);
                bf[t] = *reinterpret_cast<const bf16x8*>(&Bs[(wn * 64 + t * 16 + l15) * 64 + ca]);
            }
#pragma unroll
            for (int mt = 0; mt < 4; ++mt)
#pragma unroll
                for (int nt = 0; nt < 4; ++nt)
                    acc[mt][nt] = __builtin_amdgcn_mfma_f32_16x16x32_bf16(af[mt], bf[nt], acc[mt][nt], 0, 0, 0);
        }
    }

#pragma unroll
    for (int mt = 0; mt < 4; ++mt)
#pragma unroll
        for (int nt = 0; nt < 4; ++nt)
#pragma unroll
            for (int r = 0; r < 4; ++r) {
                const int m = row0 + wm * 64 + mt * 16 + quad * 4 + r;
                const int n = col0 + wn * 64 + nt * 16 + l15;
                const int b = m >> 10, t = m & 1023;
                const int h = n >> 6,  d = n & 63;
                const us vb = f2bf(acc[mt][nt][r]);
                if (vtrans)  out[((size_t)((b * 16 + h) * 64 + d)) * 1024 + t] = vb;
                else         out[((size_t)(b * 16 + h) * 1024 + t) * 64 + d] = vb;
            }
}

__global__ __launch_bounds__(256) void proj_gf(
    const us* __restrict__ A, const us* __restrict__ Bm, float* __restrict__ C)
{
    __shared__ __align__(16) us As[128 * 64];
    __shared__ __align__(16) us Bs[128 * 64];

    const int tid  = threadIdx.x;
    const int lane = tid & 63;
    const int w    = tid >> 6;
    const int quad = lane >> 4;
    const int l15  = lane & 15;
    const int wm   = w >> 1, wn = w & 1;
    const int row0 = blockIdx.x * 128;
    const int col0 = blockIdx.y * 128;
    const int x7   = l15 & 7;
    const int ca0  = (quad ^ x7) * 8;
    const int ca1  = ((4 + quad) ^ x7) * 8;

    const us* pa[4]; const us* pb[4];
#pragma unroll
    for (int i = 0; i < 4; ++i) {
        const int idx = tid + i * 256;
        const int r   = idx >> 3;
        const int c8  = ((idx & 7) ^ (r & 7)) * 8;
        pa[i] = A  + (size_t)(row0 + r) * K_ + c8;
        pb[i] = Bm + (size_t)(col0 + r) * K_ + c8;
    }

    f32x4 acc[4][4] = {};
    for (int k0 = 0; k0 < K_; k0 += 64) {
        __syncthreads();
#pragma unroll
        for (int i = 0; i < 4; ++i) {
            async_cp16(pa[i], &As[(tid + i * 256) * 8]);
            async_cp16(pb[i], &Bs[(tid + i * 256) * 8]);
            pa[i] += 64; pb[i] += 64;
        }
        __syncthreads();
#pragma unroll
        for (int kk = 0; kk < 2; ++kk) {
            const int ca = kk ? ca1 : ca0;
            bf16x8 af[4], bf[4];
#pragma unroll
            for (int t = 0; t < 4; ++t) {
                af[t] = *reinterpret_cast<const bf16x8*>(&As[(wm * 64 + t * 16 + l15) * 64 + ca]);
                bf[t] = *reinterpret_cast<const bf16x8*>(&Bs[(wn * 64 + t * 16 + l15) * 64 + ca]);
            }
#pragma unroll
            for (int mt = 0; mt < 4; ++mt)
#pragma unroll
                for (int nt = 0; nt < 4; ++nt)
                    acc[mt][nt] = __builtin_amdgcn_mfma_f32_16x16x32_bf16(af[mt], bf[nt], acc[mt][nt], 0, 0, 0);
        }
    }

    // f32 output: 16-lane runs are already 64B-contiguous — store direct.
#pragma unroll
    for (int mt = 0; mt < 4; ++mt)
#pragma unroll
        for (int nt = 0; nt < 4; ++nt)
#pragma unroll
            for (int r = 0; r < 4; ++r) {
                const int m = row0 + wm * 64 + mt * 16 + quad * 4 + r;
                const int n = col0 + wn * 64 + nt * 16 + l15;
                C[(size_t)m * E_ + n] = acc[mt][nt][r];
            }
}

// ---------------------------------------------------------------------------
// attn_v8x: attn_v8 body (r19/r28 best-measured) + XCD-aware 1-D grid decode
// (r24-proven bijective): bh=(id&7)|((id>>6)<<3), px=(id>>3)&7 -> id%8 (the
// XCD round-robin slot) is constant across the 8 px-siblings of one bh, so
// they share one XCD's L2 copy of K/V instead of 8 XCDs each re-fetching.
// ---------------------------------------------------------------------------
#define CSCALE 0.18033688011112042f   // 0.125 * log2(e)

__global__ __launch_bounds__(256) void attn_v8x(
    const us* __restrict__ Q, const us* __restrict__ K,
    const us* __restrict__ VT, us* __restrict__ O)
{
    const int id = blockIdx.x;
    const int bh = (id & 7) | ((id >> 6) << 3);
    const int px = (id >> 3) & 7;
    const int tA = px, tB = 15 - px;    // uniform work: (p+1)+(16-p)=17 units
    const size_t base  = (size_t)bh * T_ * HS_;
    const size_t baseT = (size_t)bh * HS_ * T_;
    const int tid  = threadIdx.x;
    const int w    = tid >> 6;
    const int lane = tid & 63;
    const int quad = lane >> 4;
    const int l15  = lane & 15;

    __shared__ __align__(16) us kt[64][72];
    __shared__ __align__(16) us vt[64][72];
    __shared__ __align__(16) us psA[4][16][72];
    __shared__ __align__(16) us psB[4][16][72];

    const int rowA = tA * 64 + w * 16;
    const int rowB = tB * 64 + w * 16;

    bf16x8 qfA0, qfA1, qfB0, qfB1;
    {
        const us* qa = Q + base + (size_t)(rowA + l15) * HS_ + quad * 8;
        const us* qb = Q + base + (size_t)(rowB + l15) * HS_ + quad * 8;
        qfA0 = *reinterpret_cast<const bf16x8*>(qa);
        qfA1 = *reinterpret_cast<const bf16x8*>(qa + 32);
        qfB0 = *reinterpret_cast<const bf16x8*>(qb);
        qfB1 = *reinterpret_cast<const bf16x8*>(qb + 32);
    }

    // staging geometry: 2 x 16B per thread over the 64x64 tiles
    const int sr0 = tid >> 3;                 // rows 0..31   (i=0)
    const int sc0 = (tid & 7) * 8;
    const int sr1 = sr0 + 32;                 // rows 32..63  (i=1)

    // hoisted prefetch pointers (K: +64 rows/chunk; VT: +64 cols/chunk)
    const us* kp0 = K + base + (size_t)sr0 * HS_ + sc0;
    const us* kp1 = K + base + (size_t)sr1 * HS_ + sc0;
    const us* vp0 = VT + baseT + (size_t)sr0 * T_ + sc0;
    const us* vp1 = VT + baseT + (size_t)sr1 * T_ + sc0;

    float lA[4] = {0.f, 0.f, 0.f, 0.f}, lB[4] = {0.f, 0.f, 0.f, 0.f};
    f32x4 oA[4] = {}, oB[4] = {};

    bf16x8 kr0, kr1, vr0, vr1;
    // prologue: issue chunk-0 loads
    kr0 = *reinterpret_cast<const bf16x8*>(kp0);
    kr1 = *reinterpret_cast<const bf16x8*>(kp1);
    vr0 = *reinterpret_cast<const bf16x8*>(vp0);
    vr1 = *reinterpret_cast<const bf16x8*>(vp1);

    const int nch = tB + 1;
    for (int ch = 0; ch < nch; ++ch) {
        const int s0 = ch * 64;
        const bool actA = (ch <= tA);

        __syncthreads();                // prior chunk's LDS readers done
        *reinterpret_cast<bf16x8*>(&kt[sr0][sc0]) = kr0;   // vmcnt wait auto
        *reinterpret_cast<bf16x8*>(&kt[sr1][sc0]) = kr1;
        *reinterpret_cast<bf16x8*>(&vt[sr0][sc0]) = vr0;
        *reinterpret_cast<bf16x8*>(&vt[sr1][sc0]) = vr1;
        __syncthreads();                // LDS tile ready

        // issue NEXT chunk's loads; latency hides under this chunk's compute
        if (ch + 1 < nch) {
            kp0 += 64 * HS_; kp1 += 64 * HS_; vp0 += 64; vp1 += 64;
            kr0 = *reinterpret_cast<const bf16x8*>(kp0);
            kr1 = *reinterpret_cast<const bf16x8*>(kp1);
            vr0 = *reinterpret_cast<const bf16x8*>(vp0);
            vr1 = *reinterpret_cast<const bf16x8*>(vp1);
        }

        // ---- QK^T: K fragments read ONCE from LDS, shared across tiles ----
        f32x4 sA[4] = {}, sB[4] = {};
#pragma unroll
        for (int nt = 0; nt < 4; ++nt) {
            bf16x8 kf0 = *reinterpret_cast<const bf16x8*>(&kt[nt * 16 + l15][quad * 8]);
            bf16x8 kf1 = *reinterpret_cast<const bf16x8*>(&kt[nt * 16 + l15][quad * 8 + 32]);
            sB[nt] = __builtin_amdgcn_mfma_f32_16x16x32_bf16(qfB0, kf0, sB[nt], 0, 0, 0);
            sB[nt] = __builtin_amdgcn_mfma_f32_16x16x32_bf16(qfB1, kf1, sB[nt], 0, 0, 0);
            if (actA) {
                sA[nt] = __builtin_amdgcn_mfma_f32_16x16x32_bf16(qfA0, kf0, sA[nt], 0, 0, 0);
                sA[nt] = __builtin_amdgcn_mfma_f32_16x16x32_bf16(qfA1, kf1, sA[nt], 0, 0, 0);
            }
        }
        if (ch == tB) {
#pragma unroll
            for (int nt = 0; nt < 4; ++nt)
#pragma unroll
                for (int r = 0; r < 4; ++r)
                    if (s0 + nt * 16 + l15 > rowB + quad * 4 + r) sB[nt][r] = -1e30f;
        }
        if (ch == tA) {
#pragma unroll
            for (int nt = 0; nt < 4; ++nt)
#pragma unroll
                for (int r = 0; r < 4; ++r)
                    if (s0 + nt * 16 + l15 > rowA + quad * 4 + r) sA[nt][r] = -1e30f;
        }

        // ---- exp2, partial sums, P -> LDS (per-wave, no barrier) ----
#pragma unroll
        for (int r = 0; r < 4; ++r)
#pragma unroll
            for (int nt = 0; nt < 4; ++nt) {
                const float pB = exp2f(sB[nt][r] * CSCALE);   // masked -> 0
                lB[r] += pB;
                psB[w][quad * 4 + r][nt * 16 + l15] = f2bf_t(pB);
            }
        if (actA) {
#pragma unroll
            for (int r = 0; r < 4; ++r)
#pragma unroll
                for (int nt = 0; nt < 4; ++nt) {
                    const float pA = exp2f(sA[nt][r] * CSCALE);
                    lA[r] += pA;
                    psA[w][quad * 4 + r][nt * 16 + l15] = f2bf_t(pA);
                }
        }

        // ---- P fragments back from LDS (same wave) ----
        bf16x8 pfB0 = *reinterpret_cast<const bf16x8*>(&psB[w][l15][quad * 8]);
        bf16x8 pfB1 = *reinterpret_cast<const bf16x8*>(&psB[w][l15][quad * 8 + 32]);
        bf16x8 pfA0, pfA1;
        if (actA) {
            pfA0 = *reinterpret_cast<const bf16x8*>(&psA[w][l15][quad * 8]);
            pfA1 = *reinterpret_cast<const bf16x8*>(&psA[w][l15][quad * 8 + 32]);
        }

        // ---- PV, V fragments from LDS, shared across tiles ----
#pragma unroll
        for (int dt = 0; dt < 4; ++dt) {
            bf16x8 vf0 = *reinterpret_cast<const bf16x8*>(&vt[dt * 16 + l15][quad * 8]);
            bf16x8 vf1 = *reinterpret_cast<const bf16x8*>(&vt[dt * 16 + l15][quad * 8 + 32]);
            oB[dt] = __builtin_amdgcn_mfma_f32_16x16x32_bf16(pfB0, vf0, oB[dt], 0, 0, 0);
            oB[dt] = __builtin_amdgcn_mfma_f32_16x16x32_bf16(pfB1, vf1, oB[dt], 0, 0, 0);
            if (actA) {
                oA[dt] = __builtin_amdgcn_mfma_f32_16x16x32_bf16(pfA0, vf0, oA[dt], 0, 0, 0);
                oA[dt] = __builtin_amdgcn_mfma_f32_16x16x32_bf16(pfA1, vf1, oA[dt], 0, 0, 0);
            }
        }
    }

    // epilogue: one 16-lane sum reduction per row, then normalize + write
#pragma unroll
    for (int r = 0; r < 4; ++r) {
#pragma unroll
        for (int off = 1; off < 16; off <<= 1) {
            lA[r] += __shfl_xor(lA[r], off);
            lB[r] += __shfl_xor(lB[r], off);
        }
    }
    const int b = bh >> 4, h = bh & 15;
#pragma unroll
    for (int r = 0; r < 4; ++r) {
        const float invA = 1.f / lA[r];
        const float invB = 1.f / lB[r];
        const size_t offA = ((size_t)b * T_ + rowA + quad * 4 + r) * E_ + h * HS_;
        const size_t offB = ((size_t)b * T_ + rowB + quad * 4 + r) * E_ + h * HS_;
#pragma unroll
        for (int dt = 0; dt < 4; ++dt) {
            O[offA + dt * 16 + l15] = f2bf(oA[dt][r] * invA);
            O[offB + dt * 16 + l15] = f2bf(oB[dt][r] * invB);
        }
    }
}

// ===========================================================================
extern "C" void kernel_launch(void* const* d_in, const int* in_sizes, int n_in,
                              void* d_out, int out_size, void* d_ws, size_t ws_size,
                              hipStream_t stream) {
    // setup_inputs order: x, Wk, Wq, Wv, Wproj, i  (all float32)
    const float* x  = (const float*)d_in[0];
    const float* Wk = (const float*)d_in[1];
    const float* Wq = (const float*)d_in[2];
    const float* Wv = (const float*)d_in[3];
    const float* Wp = (const float*)d_in[4];

    const size_t qe = (size_t)B_ * H_ * T_ * HS_;   // 8,388,608 elems
    const size_t we = (size_t)E_ * E_;              // 1,048,576 elems

    // ws: xb(16M, reused as o) | wq | wk | wv | wp | q | k | vT  (~76 MB)
    us* xb = (us*)d_ws;
    us* wq = xb + qe;
    us* wk = wq + we;
    us* wv = wk + we;
    us* wp = wv + we;
    us* q  = wp + we;
    us* k  = q + qe;
    us* vT = k + qe;
    us* o  = xb;   // xb dead after qkv_gf

    cvt_kernel<<<dim3(4096, 5), 256, 0, stream>>>(x, Wq, Wk, Wv, Wp,
                                                  xb, wq, wk, wv, wp);
    qkv_gf<<<dim3(64, 8, 3), 256, 0, stream>>>(xb, wq, wk, wv, q, k, vT);
    attn_v8x<<<dim3(1024), 256, 0, stream>>>(q, k, vT, o);
    proj_gf<<<dim3(64, 8), 256, 0, stream>>>(o, wp, (float*)d_out);
}

// Round 17
// 237.443 us; speedup vs baseline: 1.0365x; 1.0365x over previous
//
#include <hip/hip_runtime.h>

// (B,T,E,H,HS) = (8,1024,1024,16,64). Inputs/output: float32 (proven r6-r12).
// Internals bf16 MFMA. r14 = BK=64 XOR-swizzled GEMM (conflicts 6.29M -> 0).
// r19 = hoisted staging pointers. r28 = r19 byte-exact = SESSION BEST
// (245.9us). r29 = XCD swizzle on attn_v8: NULL (v8 not traffic-bound; attn
// CLOSED). Ledger of nulls/regressions: 2-phase GEMM (r21), swapped-QK K=16
// PV (r22), async-dbuf attn (r23-26), ones-MFMA on v8 (r27).
// r30 = OCCUPANCY: qkv/proj run 2 blocks/CU because unified VGPR+AGPR =
// 112+64 = 176/wave -> 2 waves/SIMD (m69 halving points; matches measured
// 19.5%). __launch_bounds__(256,3) budgets 170/wave -- allocator only needs
// to shave 6 VGPRs (vs r11's disaster which forced a far harsher bound).
// 3 blocks/CU lets other blocks' MFMA cover each block's barrier drain.
// Pre-commit: scratch/spill or regression -> revert to (256).
#define B_  8
#define T_  1024
#define E_  1024
#define H_  16
#define HS_ 64
#define K_  1024

typedef __bf16 bf16x8 __attribute__((ext_vector_type(8)));
typedef float  f32x4  __attribute__((ext_vector_type(4)));
typedef unsigned short us;

__device__ __forceinline__ us f2bf(float f) {           // RNE
    union { float f; unsigned int i; } c; c.f = f;
    unsigned int x = c.i;
    return (us)((x + 0x7fff + ((x >> 16) & 1)) >> 16);
}
__device__ __forceinline__ us f2bf_t(float f) {         // truncate (P only)
    union { float f; unsigned int i; } c; c.f = f;
    return (us)(c.i >> 16);
}
__device__ __forceinline__ bf16x8 cvt8(const float* p) {
    float4 a = *reinterpret_cast<const float4*>(p);
    float4 b = *reinterpret_cast<const float4*>(p + 4);
    union { bf16x8 v; us u[8]; } c;
    c.u[0] = f2bf(a.x); c.u[1] = f2bf(a.y); c.u[2] = f2bf(a.z); c.u[3] = f2bf(a.w);
    c.u[4] = f2bf(b.x); c.u[5] = f2bf(b.y); c.u[6] = f2bf(b.z); c.u[7] = f2bf(b.w);
    return c.v;
}
// Async global->LDS 16B/lane; LDS dest = wave-uniform base + lane*16 (m97/m104).
__device__ __forceinline__ void async_cp16(const us* g, us* l) {
    __builtin_amdgcn_global_load_lds((const unsigned int*)g, (unsigned int*)l, 16, 0, 0);
}

// ---------------------------------------------------------------------------
// One-shot f32 -> bf16 conversion of x and the four weight matrices.
// ---------------------------------------------------------------------------
__global__ __launch_bounds__(256) void cvt_kernel(
    const float* __restrict__ sx, const float* __restrict__ sq,
    const float* __restrict__ sk, const float* __restrict__ sv,
    const float* __restrict__ sp,
    us* __restrict__ dx, us* __restrict__ dq, us* __restrict__ dk,
    us* __restrict__ dv, us* __restrict__ dp)
{
    const int y = blockIdx.y;
    const float* src = (y == 0) ? sx : (y == 1) ? sq : (y == 2) ? sk : (y == 3) ? sv : sp;
    us*          dst = (y == 0) ? dx : (y == 1) ? dq : (y == 2) ? dk : (y == 3) ? dv : dp;
    const size_t n = (y == 0) ? (size_t)B_ * T_ * E_ : (size_t)E_ * E_;
    const size_t i = ((size_t)blockIdx.x * 256 + threadIdx.x) * 8;
    if (i >= n) return;
    *reinterpret_cast<bf16x8*>(dst + i) = cvt8(src + i);
}

// ---------------------------------------------------------------------------
// 128x128 all-bf16 GEMM, BK=64, global_load_lds width-16 staging, XOR-swizzled
// LDS (conflict-free, r14), hoisted pointers (r19), min-3-waves/SIMD bounds
// (r30: 2->3 blocks/CU so cross-block MFMA covers barrier drains).
// Do NOT grow the tile (r10: 216 VGPR collapse).
// ---------------------------------------------------------------------------
__global__ __launch_bounds__(256, 3) void qkv_gf(
    const us* __restrict__ A,
    const us* __restrict__ Wq, const us* __restrict__ Wk, const us* __restrict__ Wv,
    us* __restrict__ q, us* __restrict__ k, us* __restrict__ vT)
{
    const int type = blockIdx.z;
    const us* Bm = (type == 0) ? Wq : (type == 1) ? Wk : Wv;
    us* out      = (type == 0) ? q  : (type == 1) ? k  : vT;
    const int vtrans = (type == 2);

    __shared__ __align__(16) us As[128 * 64];
    __shared__ __align__(16) us Bs[128 * 64];

    const int tid  = threadIdx.x;
    const int lane = tid & 63;
    const int w    = tid >> 6;
    const int quad = lane >> 4;
    const int l15  = lane & 15;
    const int wm   = w >> 1, wn = w & 1;
    const int row0 = blockIdx.x * 128;
    const int col0 = blockIdx.y * 128;
    const int x7   = l15 & 7;          // fragment row & 7 (rows are +multiple of 8)
    const int ca0  = (quad ^ x7) * 8;          // swizzled read chunk, kk=0
    const int ca1  = ((4 + quad) ^ x7) * 8;    // kk=1

    // hoisted staging pointers: advance 64 elems (128B) per K-step
    const us* pa[4]; const us* pb[4];
#pragma unroll
    for (int i = 0; i < 4; ++i) {
        const int idx = tid + i * 256;          // 0..1023
        const int r   = idx >> 3;               // tile row 0..127
        const int c8  = ((idx & 7) ^ (r & 7)) * 8;  // inverse-swizzled src chunk
        pa[i] = A  + (size_t)(row0 + r) * K_ + c8;
        pb[i] = Bm + (size_t)(col0 + r) * K_ + c8;
    }

    f32x4 acc[4][4] = {};
    for (int k0 = 0; k0 < K_; k0 += 64) {
        __syncthreads();
#pragma unroll
        for (int i = 0; i < 4; ++i) {
            async_cp16(pa[i], &As[(tid + i * 256) * 8]);
            async_cp16(pb[i], &Bs[(tid + i * 256) * 8]);
            pa[i] += 64; pb[i] += 64;
        }
        __syncthreads();
#pragma unroll
        for (int kk = 0; kk < 2; ++kk) {
            const int ca = kk ? ca1 : ca0;
            bf16x8 af[4], bf[4];
#pragma unroll
            for (int t = 0; t < 4; ++t) {
                af[t] = *reinterpret_cast<const bf16x8*>(&As[(wm * 64 + t * 16 + l15) * 64 + ca]);
                bf[t] = *reinterpret_cast<const bf16x8*>(&Bs[(wn * 64 + t * 16 + l15) * 64 + ca]);
            }
#pragma unroll
            for (int mt = 0; mt < 4; ++mt)
#pragma unroll
                for (int nt = 0; nt < 4; ++nt)
                    acc[mt][nt] = __builtin_amdgcn_mfma_f32_16x16x32_bf16(af[mt], bf[nt], acc[mt][nt], 0, 0, 0);
        }
    }

#pragma unroll
    for (int mt = 0; mt < 4; ++mt)
#pragma unroll
        for (int nt = 0; nt < 4; ++nt)
#pragma unroll
            for (int r = 0; r < 4; ++r) {
                const int m = row0 + wm * 64 + mt * 16 + quad * 4 + r;
                const int n = col0 + wn * 64 + nt * 16 + l15;
                const int b = m >> 10, t = m & 1023;
                const int h = n >> 6,  d = n & 63;
                const us vb = f2bf(acc[mt][nt][r]);
                if (vtrans)  out[((size_t)((b * 16 + h) * 64 + d)) * 1024 + t] = vb;
                else         out[((size_t)(b * 16 + h) * 1024 + t) * 64 + d] = vb;
            }
}

__global__ __launch_bounds__(256, 3) void proj_gf(
    const us* __restrict__ A, const us* __restrict__ Bm, float* __restrict__ C)
{
    __shared__ __align__(16) us As[128 * 64];
    __shared__ __align__(16) us Bs[128 * 64];

    const int tid  = threadIdx.x;
    const int lane = tid & 63;
    const int w    = tid >> 6;
    const int quad = lane >> 4;
    const int l15  = lane & 15;
    const int wm   = w >> 1, wn = w & 1;
    const int row0 = blockIdx.x * 128;
    const int col0 = blockIdx.y * 128;
    const int x7   = l15 & 7;
    const int ca0  = (quad ^ x7) * 8;
    const int ca1  = ((4 + quad) ^ x7) * 8;

    const us* pa[4]; const us* pb[4];
#pragma unroll
    for (int i = 0; i < 4; ++i) {
        const int idx = tid + i * 256;
        const int r   = idx >> 3;
        const int c8  = ((idx & 7) ^ (r & 7)) * 8;
        pa[i] = A  + (size_t)(row0 + r) * K_ + c8;
        pb[i] = Bm + (size_t)(col0 + r) * K_ + c8;
    }

    f32x4 acc[4][4] = {};
    for (int k0 = 0; k0 < K_; k0 += 64) {
        __syncthreads();
#pragma unroll
        for (int i = 0; i < 4; ++i) {
            async_cp16(pa[i], &As[(tid + i * 256) * 8]);
            async_cp16(pb[i], &Bs[(tid + i * 256) * 8]);
            pa[i] += 64; pb[i] += 64;
        }
        __syncthreads();
#pragma unroll
        for (int kk = 0; kk < 2; ++kk) {
            const int ca = kk ? ca1 : ca0;
            bf16x8 af[4], bf[4];
#pragma unroll
            for (int t = 0; t < 4; ++t) {
                af[t] = *reinterpret_cast<const bf16x8*>(&As[(wm * 64 + t * 16 + l15) * 64 + ca]);
                bf[t] = *reinterpret_cast<const bf16x8*>(&Bs[(wn * 64 + t * 16 + l15) * 64 + ca]);
            }
#pragma unroll
            for (int mt = 0; mt < 4; ++mt)
#pragma unroll
                for (int nt = 0; nt < 4; ++nt)
                    acc[mt][nt] = __builtin_amdgcn_mfma_f32_16x16x32_bf16(af[mt], bf[nt], acc[mt][nt], 0, 0, 0);
        }
    }

    // f32 output: 16-lane runs are already 64B-contiguous — store direct.
#pragma unroll
    for (int mt = 0; mt < 4; ++mt)
#pragma unroll
        for (int nt = 0; nt < 4; ++nt)
#pragma unroll
            for (int r = 0; r < 4; ++r) {
                const int m = row0 + wm * 64 + mt * 16 + quad * 4 + r;
                const int n = col0 + wn * 64 + nt * 16 + l15;
                C[(size_t)m * E_ + n] = acc[mt][nt][r];
            }
}

// ---------------------------------------------------------------------------
// attn_v8: causal-paired tiles + NO-MAX online softmax + T14 async staging.
// Per chunk: [barrier] write staged regs->LDS [barrier] issue NEXT chunk's
// global loads (latency hides under compute) then QK/exp/PV from LDS.
// K fragments read from LDS once, shared by both tiles. Prefetch pointers
// hoisted. BEST-MEASURED attn; XCD swizzle NULL on this body (r29) -> CLOSED.
// ---------------------------------------------------------------------------
#define CSCALE 0.18033688011112042f   // 0.125 * log2(e)

__global__ __launch_bounds__(256) void attn_v8(
    const us* __restrict__ Q, const us* __restrict__ K,
    const us* __restrict__ VT, us* __restrict__ O)
{
    const int px = blockIdx.x;          // 0..7
    const int bh = blockIdx.y;
    const int tA = px, tB = 15 - px;    // uniform work: (p+1)+(16-p)=17 units
    const size_t base  = (size_t)bh * T_ * HS_;
    const size_t baseT = (size_t)bh * HS_ * T_;
    const int tid  = threadIdx.x;
    const int w    = tid >> 6;
    const int lane = tid & 63;
    const int quad = lane >> 4;
    const int l15  = lane & 15;

    __shared__ __align__(16) us kt[64][72];
    __shared__ __align__(16) us vt[64][72];
    __shared__ __align__(16) us psA[4][16][72];
    __shared__ __align__(16) us psB[4][16][72];

    const int rowA = tA * 64 + w * 16;
    const int rowB = tB * 64 + w * 16;

    bf16x8 qfA0, qfA1, qfB0, qfB1;
    {
        const us* qa = Q + base + (size_t)(rowA + l15) * HS_ + quad * 8;
        const us* qb = Q + base + (size_t)(rowB + l15) * HS_ + quad * 8;
        qfA0 = *reinterpret_cast<const bf16x8*>(qa);
        qfA1 = *reinterpret_cast<const bf16x8*>(qa + 32);
        qfB0 = *reinterpret_cast<const bf16x8*>(qb);
        qfB1 = *reinterpret_cast<const bf16x8*>(qb + 32);
    }

    // staging geometry: 2 x 16B per thread over the 64x64 tiles
    const int sr0 = tid >> 3;                 // rows 0..31   (i=0)
    const int sc0 = (tid & 7) * 8;
    const int sr1 = sr0 + 32;                 // rows 32..63  (i=1)

    // hoisted prefetch pointers (K: +64 rows/chunk; VT: +64 cols/chunk)
    const us* kp0 = K + base + (size_t)sr0 * HS_ + sc0;
    const us* kp1 = K + base + (size_t)sr1 * HS_ + sc0;
    const us* vp0 = VT + baseT + (size_t)sr0 * T_ + sc0;
    const us* vp1 = VT + baseT + (size_t)sr1 * T_ + sc0;

    float lA[4] = {0.f, 0.f, 0.f, 0.f}, lB[4] = {0.f, 0.f, 0.f, 0.f};
    f32x4 oA[4] = {}, oB[4] = {};

    bf16x8 kr0, kr1, vr0, vr1;
    // prologue: issue chunk-0 loads
    kr0 = *reinterpret_cast<const bf16x8*>(kp0);
    kr1 = *reinterpret_cast<const bf16x8*>(kp1);
    vr0 = *reinterpret_cast<const bf16x8*>(vp0);
    vr1 = *reinterpret_cast<const bf16x8*>(vp1);

    const int nch = tB + 1;
    for (int ch = 0; ch < nch; ++ch) {
        const int s0 = ch * 64;
        const bool actA = (ch <= tA);

        __syncthreads();                // prior chunk's LDS readers done
        *reinterpret_cast<bf16x8*>(&kt[sr0][sc0]) = kr0;   // vmcnt wait auto
        *reinterpret_cast<bf16x8*>(&kt[sr1][sc0]) = kr1;
        *reinterpret_cast<bf16x8*>(&vt[sr0][sc0]) = vr0;
        *reinterpret_cast<bf16x8*>(&vt[sr1][sc0]) = vr1;
        __syncthreads();                // LDS tile ready

        // issue NEXT chunk's loads; latency hides under this chunk's compute
        if (ch + 1 < nch) {
            kp0 += 64 * HS_; kp1 += 64 * HS_; vp0 += 64; vp1 += 64;
            kr0 = *reinterpret_cast<const bf16x8*>(kp0);
            kr1 = *reinterpret_cast<const bf16x8*>(kp1);
            vr0 = *reinterpret_cast<const bf16x8*>(vp0);
            vr1 = *reinterpret_cast<const bf16x8*>(vp1);
        }

        // ---- QK^T: K fragments read ONCE from LDS, shared across tiles ----
        f32x4 sA[4] = {}, sB[4] = {};
#pragma unroll
        for (int nt = 0; nt < 4; ++nt) {
            bf16x8 kf0 = *reinterpret_cast<const bf16x8*>(&kt[nt * 16 + l15][quad * 8]);
            bf16x8 kf1 = *reinterpret_cast<const bf16x8*>(&kt[nt * 16 + l15][quad * 8 + 32]);
            sB[nt] = __builtin_amdgcn_mfma_f32_16x16x32_bf16(qfB0, kf0, sB[nt], 0, 0, 0);
            sB[nt] = __builtin_amdgcn_mfma_f32_16x16x32_bf16(qfB1, kf1, sB[nt], 0, 0, 0);
            if (actA) {
                sA[nt] = __builtin_amdgcn_mfma_f32_16x16x32_bf16(qfA0, kf0, sA[nt], 0, 0, 0);
                sA[nt] = __builtin_amdgcn_mfma_f32_16x16x32_bf16(qfA1, kf1, sA[nt], 0, 0, 0);
            }
        }
        if (ch == tB) {
#pragma unroll
            for (int nt = 0; nt < 4; ++nt)
#pragma unroll
                for (int r = 0; r < 4; ++r)
                    if (s0 + nt * 16 + l15 > rowB + quad * 4 + r) sB[nt][r] = -1e30f;
        }
        if (ch == tA) {
#pragma unroll
            for (int nt = 0; nt < 4; ++nt)
#pragma unroll
                for (int r = 0; r < 4; ++r)
                    if (s0 + nt * 16 + l15 > rowA + quad * 4 + r) sA[nt][r] = -1e30f;
        }

        // ---- exp2, partial sums, P -> LDS (per-wave, no barrier) ----
#pragma unroll
        for (int r = 0; r < 4; ++r)
#pragma unroll
            for (int nt = 0; nt < 4; ++nt) {
                const float pB = exp2f(sB[nt][r] * CSCALE);   // masked -> 0
                lB[r] += pB;
                psB[w][quad * 4 + r][nt * 16 + l15] = f2bf_t(pB);
            }
        if (actA) {
#pragma unroll
            for (int r = 0; r < 4; ++r)
#pragma unroll
                for (int nt = 0; nt < 4; ++nt) {
                    const float pA = exp2f(sA[nt][r] * CSCALE);
                    lA[r] += pA;
                    psA[w][quad * 4 + r][nt * 16 + l15] = f2bf_t(pA);
                }
        }

        // ---- P fragments back from LDS (same wave) ----
        bf16x8 pfB0 = *reinterpret_cast<const bf16x8*>(&psB[w][l15][quad * 8]);
        bf16x8 pfB1 = *reinterpret_cast<const bf16x8*>(&psB[w][l15][quad * 8 + 32]);
        bf16x8 pfA0, pfA1;
        if (actA) {
            pfA0 = *reinterpret_cast<const bf16x8*>(&psA[w][l15][quad * 8]);
            pfA1 = *reinterpret_cast<const bf16x8*>(&psA[w][l15][quad * 8 + 32]);
        }

        // ---- PV, V fragments from LDS, shared across tiles ----
#pragma unroll
        for (int dt = 0; dt < 4; ++dt) {
            bf16x8 vf0 = *reinterpret_cast<const bf16x8*>(&vt[dt * 16 + l15][quad * 8]);
            bf16x8 vf1 = *reinterpret_cast<const bf16x8*>(&vt[dt * 16 + l15][quad * 8 + 32]);
            oB[dt] = __builtin_amdgcn_mfma_f32_16x16x32_bf16(pfB0, vf0, oB[dt], 0, 0, 0);
            oB[dt] = __builtin_amdgcn_mfma_f32_16x16x32_bf16(pfB1, vf1, oB[dt], 0, 0, 0);
            if (actA) {
                oA[dt] = __builtin_amdgcn_mfma_f32_16x16x32_bf16(pfA0, vf0, oA[dt], 0, 0, 0);
                oA[dt] = __builtin_amdgcn_mfma_f32_16x16x32_bf16(pfA1, vf1, oA[dt], 0, 0, 0);
            }
        }
    }

    // epilogue: one 16-lane sum reduction per row, then normalize + write
#pragma unroll
    for (int r = 0; r < 4; ++r) {
#pragma unroll
        for (int off = 1; off < 16; off <<= 1) {
            lA[r] += __shfl_xor(lA[r], off);
            lB[r] += __shfl_xor(lB[r], off);
        }
    }
    const int b = bh >> 4, h = bh & 15;
#pragma unroll
    for (int r = 0; r < 4; ++r) {
        const float invA = 1.f / lA[r];
        const float invB = 1.f / lB[r];
        const size_t offA = ((size_t)b * T_ + rowA + quad * 4 + r) * E_ + h * HS_;
        const size_t offB = ((size_t)b * T_ + rowB + quad * 4 + r) * E_ + h * HS_;
#pragma unroll
        for (int dt = 0; dt < 4; ++dt) {
            O[offA + dt * 16 + l15] = f2bf(oA[dt][r] * invA);
            O[offB + dt * 16 + l15] = f2bf(oB[dt][r] * invB);
        }
    }
}

// ===========================================================================
extern "C" void kernel_launch(void* const* d_in, const int* in_sizes, int n_in,
                              void* d_out, int out_size, void* d_ws, size_t ws_size,
                              hipStream_t stream) {
    // setup_inputs order: x, Wk, Wq, Wv, Wproj, i  (all float32)
    const float* x  = (const float*)d_in[0];
    const float* Wk = (const float*)d_in[1];
    const float* Wq = (const float*)d_in[2];
    const float* Wv = (const float*)d_in[3];
    const float* Wp = (const float*)d_in[4];

    const size_t qe = (size_t)B_ * H_ * T_ * HS_;   // 8,388,608 elems
    const size_t we = (size_t)E_ * E_;              // 1,048,576 elems

    // ws: xb(16M, reused as o) | wq | wk | wv | wp | q | k | vT  (~76 MB)
    us* xb = (us*)d_ws;
    us* wq = xb + qe;
    us* wk = wq + we;
    us* wv = wk + we;
    us* wp = wv + we;
    us* q  = wp + we;
    us* k  = q + qe;
    us* vT = k + qe;
    us* o  = xb;   // xb dead after qkv_gf

    cvt_kernel<<<dim3(4096, 5), 256, 0, stream>>>(x, Wq, Wk, Wv, Wp,
                                                  xb, wq, wk, wv, wp);
    qkv_gf<<<dim3(64, 8, 3), 256, 0, stream>>>(xb, wq, wk, wv, q, k, vT);
    attn_v8<<<dim3(8, 128), 256, 0, stream>>>(q, k, vT, o);
    proj_gf<<<dim3(64, 8), 256, 0, stream>>>(o, wp, (float*)d_out);
}

// Round 18
// 232.697 us; speedup vs baseline: 1.0576x; 1.0204x over previous
//
#include <hip/hip_runtime.h>

// (B,T,E,H,HS) = (8,1024,1024,16,64). Inputs/output: float32 (proven r6-r12).
// Internals bf16 MFMA. r14 = BK=64 XOR-swizzled GEMM (conflicts 6.29M -> 0).
// r19 = hoisted staging pointers. r28 = r19 byte-exact (245.9). r29 = XCD
// swizzle on attn: NULL (not traffic-bound). r30 = __launch_bounds__(256,3)
// on qkv/proj: WIN (qkv 79.7->71.5us, VGPR 112->72 no spill, MfmaUtil
// 25->29, total 237.4 = SESSION BEST) -- unified VGPR+AGPR 176/wave was
// capping at 2 waves/SIMD. r31 = SAME LEVER ON attn_v8: its ~112-130 VGPR
// footprint is the same 2-waves/SIMD cliff (LDS 36.9KB permits 4 blocks/CU,
// VGPR binds). One change; pre-commit: spill/regression -> revert.
#define B_  8
#define T_  1024
#define E_  1024
#define H_  16
#define HS_ 64
#define K_  1024

typedef __bf16 bf16x8 __attribute__((ext_vector_type(8)));
typedef float  f32x4  __attribute__((ext_vector_type(4)));
typedef unsigned short us;

__device__ __forceinline__ us f2bf(float f) {           // RNE
    union { float f; unsigned int i; } c; c.f = f;
    unsigned int x = c.i;
    return (us)((x + 0x7fff + ((x >> 16) & 1)) >> 16);
}
__device__ __forceinline__ us f2bf_t(float f) {         // truncate (P only)
    union { float f; unsigned int i; } c; c.f = f;
    return (us)(c.i >> 16);
}
__device__ __forceinline__ bf16x8 cvt8(const float* p) {
    float4 a = *reinterpret_cast<const float4*>(p);
    float4 b = *reinterpret_cast<const float4*>(p + 4);
    union { bf16x8 v; us u[8]; } c;
    c.u[0] = f2bf(a.x); c.u[1] = f2bf(a.y); c.u[2] = f2bf(a.z); c.u[3] = f2bf(a.w);
    c.u[4] = f2bf(b.x); c.u[5] = f2bf(b.y); c.u[6] = f2bf(b.z); c.u[7] = f2bf(b.w);
    return c.v;
}
// Async global->LDS 16B/lane; LDS dest = wave-uniform base + lane*16 (m97/m104).
__device__ __forceinline__ void async_cp16(const us* g, us* l) {
    __builtin_amdgcn_global_load_lds((const unsigned int*)g, (unsigned int*)l, 16, 0, 0);
}

// ---------------------------------------------------------------------------
// One-shot f32 -> bf16 conversion of x and the four weight matrices.
// ---------------------------------------------------------------------------
__global__ __launch_bounds__(256) void cvt_kernel(
    const float* __restrict__ sx, const float* __restrict__ sq,
    const float* __restrict__ sk, const float* __restrict__ sv,
    const float* __restrict__ sp,
    us* __restrict__ dx, us* __restrict__ dq, us* __restrict__ dk,
    us* __restrict__ dv, us* __restrict__ dp)
{
    const int y = blockIdx.y;
    const float* src = (y == 0) ? sx : (y == 1) ? sq : (y == 2) ? sk : (y == 3) ? sv : sp;
    us*          dst = (y == 0) ? dx : (y == 1) ? dq : (y == 2) ? dk : (y == 3) ? dv : dp;
    const size_t n = (y == 0) ? (size_t)B_ * T_ * E_ : (size_t)E_ * E_;
    const size_t i = ((size_t)blockIdx.x * 256 + threadIdx.x) * 8;
    if (i >= n) return;
    *reinterpret_cast<bf16x8*>(dst + i) = cvt8(src + i);
}

// ---------------------------------------------------------------------------
// 128x128 all-bf16 GEMM, BK=64, global_load_lds width-16 staging, XOR-swizzled
// LDS (conflict-free, r14), hoisted pointers (r19), min-3-waves/SIMD bounds
// (r30-proven: VGPR 112->72, 2->3 blocks/CU, qkv -10%).
// Do NOT grow the tile (r10: 216 VGPR collapse).
// ---------------------------------------------------------------------------
__global__ __launch_bounds__(256, 3) void qkv_gf(
    const us* __restrict__ A,
    const us* __restrict__ Wq, const us* __restrict__ Wk, const us* __restrict__ Wv,
    us* __restrict__ q, us* __restrict__ k, us* __restrict__ vT)
{
    const int type = blockIdx.z;
    const us* Bm = (type == 0) ? Wq : (type == 1) ? Wk : Wv;
    us* out      = (type == 0) ? q  : (type == 1) ? k  : vT;
    const int vtrans = (type == 2);

    __shared__ __align__(16) us As[128 * 64];
    __shared__ __align__(16) us Bs[128 * 64];

    const int tid  = threadIdx.x;
    const int lane = tid & 63;
    const int w    = tid >> 6;
    const int quad = lane >> 4;
    const int l15  = lane & 15;
    const int wm   = w >> 1, wn = w & 1;
    const int row0 = blockIdx.x * 128;
    const int col0 = blockIdx.y * 128;
    const int x7   = l15 & 7;          // fragment row & 7 (rows are +multiple of 8)
    const int ca0  = (quad ^ x7) * 8;          // swizzled read chunk, kk=0
    const int ca1  = ((4 + quad) ^ x7) * 8;    // kk=1

    // hoisted staging pointers: advance 64 elems (128B) per K-step
    const us* pa[4]; const us* pb[4];
#pragma unroll
    for (int i = 0; i < 4; ++i) {
        const int idx = tid + i * 256;          // 0..1023
        const int r   = idx >> 3;               // tile row 0..127
        const int c8  = ((idx & 7) ^ (r & 7)) * 8;  // inverse-swizzled src chunk
        pa[i] = A  + (size_t)(row0 + r) * K_ + c8;
        pb[i] = Bm + (size_t)(col0 + r) * K_ + c8;
    }

    f32x4 acc[4][4] = {};
    for (int k0 = 0; k0 < K_; k0 += 64) {
        __syncthreads();
#pragma unroll
        for (int i = 0; i < 4; ++i) {
            async_cp16(pa[i], &As[(tid + i * 256) * 8]);
            async_cp16(pb[i], &Bs[(tid + i * 256) * 8]);
            pa[i] += 64; pb[i] += 64;
        }
        __syncthreads();
#pragma unroll
        for (int kk = 0; kk < 2; ++kk) {
            const int ca = kk ? ca1 : ca0;
            bf16x8 af[4], bf[4];
#pragma unroll
            for (int t = 0; t < 4; ++t) {
                af[t] = *reinterpret_cast<const bf16x8*>(&As[(wm * 64 + t * 16 + l15) * 64 + ca]);
                bf[t] = *reinterpret_cast<const bf16x8*>(&Bs[(wn * 64 + t * 16 + l15) * 64 + ca]);
            }
#pragma unroll
            for (int mt = 0; mt < 4; ++mt)
#pragma unroll
                for (int nt = 0; nt < 4; ++nt)
                    acc[mt][nt] = __builtin_amdgcn_mfma_f32_16x16x32_bf16(af[mt], bf[nt], acc[mt][nt], 0, 0, 0);
        }
    }

#pragma unroll
    for (int mt = 0; mt < 4; ++mt)
#pragma unroll
        for (int nt = 0; nt < 4; ++nt)
#pragma unroll
            for (int r = 0; r < 4; ++r) {
                const int m = row0 + wm * 64 + mt * 16 + quad * 4 + r;
                const int n = col0 + wn * 64 + nt * 16 + l15;
                const int b = m >> 10, t = m & 1023;
                const int h = n >> 6,  d = n & 63;
                const us vb = f2bf(acc[mt][nt][r]);
                if (vtrans)  out[((size_t)((b * 16 + h) * 64 + d)) * 1024 + t] = vb;
                else         out[((size_t)(b * 16 + h) * 1024 + t) * 64 + d] = vb;
            }
}

__global__ __launch_bounds__(256, 3) void proj_gf(
    const us* __restrict__ A, const us* __restrict__ Bm, float* __restrict__ C)
{
    __shared__ __align__(16) us As[128 * 64];
    __shared__ __align__(16) us Bs[128 * 64];

    const int tid  = threadIdx.x;
    const int lane = tid & 63;
    const int w    = tid >> 6;
    const int quad = lane >> 4;
    const int l15  = lane & 15;
    const int wm   = w >> 1, wn = w & 1;
    const int row0 = blockIdx.x * 128;
    const int col0 = blockIdx.y * 128;
    const int x7   = l15 & 7;
    const int ca0  = (quad ^ x7) * 8;
    const int ca1  = ((4 + quad) ^ x7) * 8;

    const us* pa[4]; const us* pb[4];
#pragma unroll
    for (int i = 0; i < 4; ++i) {
        const int idx = tid + i * 256;
        const int r   = idx >> 3;
        const int c8  = ((idx & 7) ^ (r & 7)) * 8;
        pa[i] = A  + (size_t)(row0 + r) * K_ + c8;
        pb[i] = Bm + (size_t)(col0 + r) * K_ + c8;
    }

    f32x4 acc[4][4] = {};
    for (int k0 = 0; k0 < K_; k0 += 64) {
        __syncthreads();
#pragma unroll
        for (int i = 0; i < 4; ++i) {
            async_cp16(pa[i], &As[(tid + i * 256) * 8]);
            async_cp16(pb[i], &Bs[(tid + i * 256) * 8]);
            pa[i] += 64; pb[i] += 64;
        }
        __syncthreads();
#pragma unroll
        for (int kk = 0; kk < 2; ++kk) {
            const int ca = kk ? ca1 : ca0;
            bf16x8 af[4], bf[4];
#pragma unroll
            for (int t = 0; t < 4; ++t) {
                af[t] = *reinterpret_cast<const bf16x8*>(&As[(wm * 64 + t * 16 + l15) * 64 + ca]);
                bf[t] = *reinterpret_cast<const bf16x8*>(&Bs[(wn * 64 + t * 16 + l15) * 64 + ca]);
            }
#pragma unroll
            for (int mt = 0; mt < 4; ++mt)
#pragma unroll
                for (int nt = 0; nt < 4; ++nt)
                    acc[mt][nt] = __builtin_amdgcn_mfma_f32_16x16x32_bf16(af[mt], bf[nt], acc[mt][nt], 0, 0, 0);
        }
    }

    // f32 output: 16-lane runs are already 64B-contiguous — store direct.
#pragma unroll
    for (int mt = 0; mt < 4; ++mt)
#pragma unroll
        for (int nt = 0; nt < 4; ++nt)
#pragma unroll
            for (int r = 0; r < 4; ++r) {
                const int m = row0 + wm * 64 + mt * 16 + quad * 4 + r;
                const int n = col0 + wn * 64 + nt * 16 + l15;
                C[(size_t)m * E_ + n] = acc[mt][nt][r];
            }
}

// ---------------------------------------------------------------------------
// attn_v8: causal-paired tiles + NO-MAX online softmax + T14 async staging.
// Per chunk: [barrier] write staged regs->LDS [barrier] issue NEXT chunk's
// global loads (latency hides under compute) then QK/exp/PV from LDS.
// K fragments read from LDS once, shared by both tiles. Prefetch pointers
// hoisted. r31: __launch_bounds__(256,3) -- same occupancy lever that won
// r30 on the GEMMs (2->3 waves/SIMD).
// ---------------------------------------------------------------------------
#define CSCALE 0.18033688011112042f   // 0.125 * log2(e)

__global__ __launch_bounds__(256, 3) void attn_v8(
    const us* __restrict__ Q, const us* __restrict__ K,
    const us* __restrict__ VT, us* __restrict__ O)
{
    const int px = blockIdx.x;          // 0..7
    const int bh = blockIdx.y;
    const int tA = px, tB = 15 - px;    // uniform work: (p+1)+(16-p)=17 units
    const size_t base  = (size_t)bh * T_ * HS_;
    const size_t baseT = (size_t)bh * HS_ * T_;
    const int tid  = threadIdx.x;
    const int w    = tid >> 6;
    const int lane = tid & 63;
    const int quad = lane >> 4;
    const int l15  = lane & 15;

    __shared__ __align__(16) us kt[64][72];
    __shared__ __align__(16) us vt[64][72];
    __shared__ __align__(16) us psA[4][16][72];
    __shared__ __align__(16) us psB[4][16][72];

    const int rowA = tA * 64 + w * 16;
    const int rowB = tB * 64 + w * 16;

    bf16x8 qfA0, qfA1, qfB0, qfB1;
    {
        const us* qa = Q + base + (size_t)(rowA + l15) * HS_ + quad * 8;
        const us* qb = Q + base + (size_t)(rowB + l15) * HS_ + quad * 8;
        qfA0 = *reinterpret_cast<const bf16x8*>(qa);
        qfA1 = *reinterpret_cast<const bf16x8*>(qa + 32);
        qfB0 = *reinterpret_cast<const bf16x8*>(qb);
        qfB1 = *reinterpret_cast<const bf16x8*>(qb + 32);
    }

    // staging geometry: 2 x 16B per thread over the 64x64 tiles
    const int sr0 = tid >> 3;                 // rows 0..31   (i=0)
    const int sc0 = (tid & 7) * 8;
    const int sr1 = sr0 + 32;                 // rows 32..63  (i=1)

    // hoisted prefetch pointers (K: +64 rows/chunk; VT: +64 cols/chunk)
    const us* kp0 = K + base + (size_t)sr0 * HS_ + sc0;
    const us* kp1 = K + base + (size_t)sr1 * HS_ + sc0;
    const us* vp0 = VT + baseT + (size_t)sr0 * T_ + sc0;
    const us* vp1 = VT + baseT + (size_t)sr1 * T_ + sc0;

    float lA[4] = {0.f, 0.f, 0.f, 0.f}, lB[4] = {0.f, 0.f, 0.f, 0.f};
    f32x4 oA[4] = {}, oB[4] = {};

    bf16x8 kr0, kr1, vr0, vr1;
    // prologue: issue chunk-0 loads
    kr0 = *reinterpret_cast<const bf16x8*>(kp0);
    kr1 = *reinterpret_cast<const bf16x8*>(kp1);
    vr0 = *reinterpret_cast<const bf16x8*>(vp0);
    vr1 = *reinterpret_cast<const bf16x8*>(vp1);

    const int nch = tB + 1;
    for (int ch = 0; ch < nch; ++ch) {
        const int s0 = ch * 64;
        const bool actA = (ch <= tA);

        __syncthreads();                // prior chunk's LDS readers done
        *reinterpret_cast<bf16x8*>(&kt[sr0][sc0]) = kr0;   // vmcnt wait auto
        *reinterpret_cast<bf16x8*>(&kt[sr1][sc0]) = kr1;
        *reinterpret_cast<bf16x8*>(&vt[sr0][sc0]) = vr0;
        *reinterpret_cast<bf16x8*>(&vt[sr1][sc0]) = vr1;
        __syncthreads();                // LDS tile ready

        // issue NEXT chunk's loads; latency hides under this chunk's compute
        if (ch + 1 < nch) {
            kp0 += 64 * HS_; kp1 += 64 * HS_; vp0 += 64; vp1 += 64;
            kr0 = *reinterpret_cast<const bf16x8*>(kp0);
            kr1 = *reinterpret_cast<const bf16x8*>(kp1);
            vr0 = *reinterpret_cast<const bf16x8*>(vp0);
            vr1 = *reinterpret_cast<const bf16x8*>(vp1);
        }

        // ---- QK^T: K fragments read ONCE from LDS, shared across tiles ----
        f32x4 sA[4] = {}, sB[4] = {};
#pragma unroll
        for (int nt = 0; nt < 4; ++nt) {
            bf16x8 kf0 = *reinterpret_cast<const bf16x8*>(&kt[nt * 16 + l15][quad * 8]);
            bf16x8 kf1 = *reinterpret_cast<const bf16x8*>(&kt[nt * 16 + l15][quad * 8 + 32]);
            sB[nt] = __builtin_amdgcn_mfma_f32_16x16x32_bf16(qfB0, kf0, sB[nt], 0, 0, 0);
            sB[nt] = __builtin_amdgcn_mfma_f32_16x16x32_bf16(qfB1, kf1, sB[nt], 0, 0, 0);
            if (actA) {
                sA[nt] = __builtin_amdgcn_mfma_f32_16x16x32_bf16(qfA0, kf0, sA[nt], 0, 0, 0);
                sA[nt] = __builtin_amdgcn_mfma_f32_16x16x32_bf16(qfA1, kf1, sA[nt], 0, 0, 0);
            }
        }
        if (ch == tB) {
#pragma unroll
            for (int nt = 0; nt < 4; ++nt)
#pragma unroll
                for (int r = 0; r < 4; ++r)
                    if (s0 + nt * 16 + l15 > rowB + quad * 4 + r) sB[nt][r] = -1e30f;
        }
        if (ch == tA) {
#pragma unroll
            for (int nt = 0; nt < 4; ++nt)
#pragma unroll
                for (int r = 0; r < 4; ++r)
                    if (s0 + nt * 16 + l15 > rowA + quad * 4 + r) sA[nt][r] = -1e30f;
        }

        // ---- exp2, partial sums, P -> LDS (per-wave, no barrier) ----
#pragma unroll
        for (int r = 0; r < 4; ++r)
#pragma unroll
            for (int nt = 0; nt < 4; ++nt) {
                const float pB = exp2f(sB[nt][r] * CSCALE);   // masked -> 0
                lB[r] += pB;
                psB[w][quad * 4 + r][nt * 16 + l15] = f2bf_t(pB);
            }
        if (actA) {
#pragma unroll
            for (int r = 0; r < 4; ++r)
#pragma unroll
                for (int nt = 0; nt < 4; ++nt) {
                    const float pA = exp2f(sA[nt][r] * CSCALE);
                    lA[r] += pA;
                    psA[w][quad * 4 + r][nt * 16 + l15] = f2bf_t(pA);
                }
        }

        // ---- P fragments back from LDS (same wave) ----
        bf16x8 pfB0 = *reinterpret_cast<const bf16x8*>(&psB[w][l15][quad * 8]);
        bf16x8 pfB1 = *reinterpret_cast<const bf16x8*>(&psB[w][l15][quad * 8 + 32]);
        bf16x8 pfA0, pfA1;
        if (actA) {
            pfA0 = *reinterpret_cast<const bf16x8*>(&psA[w][l15][quad * 8]);
            pfA1 = *reinterpret_cast<const bf16x8*>(&psA[w][l15][quad * 8 + 32]);
        }

        // ---- PV, V fragments from LDS, shared across tiles ----
#pragma unroll
        for (int dt = 0; dt < 4; ++dt) {
            bf16x8 vf0 = *reinterpret_cast<const bf16x8*>(&vt[dt * 16 + l15][quad * 8]);
            bf16x8 vf1 = *reinterpret_cast<const bf16x8*>(&vt[dt * 16 + l15][quad * 8 + 32]);
            oB[dt] = __builtin_amdgcn_mfma_f32_16x16x32_bf16(pfB0, vf0, oB[dt], 0, 0, 0);
            oB[dt] = __builtin_amdgcn_mfma_f32_16x16x32_bf16(pfB1, vf1, oB[dt], 0, 0, 0);
            if (actA) {
                oA[dt] = __builtin_amdgcn_mfma_f32_16x16x32_bf16(pfA0, vf0, oA[dt], 0, 0, 0);
                oA[dt] = __builtin_amdgcn_mfma_f32_16x16x32_bf16(pfA1, vf1, oA[dt], 0, 0, 0);
            }
        }
    }

    // epilogue: one 16-lane sum reduction per row, then normalize + write
#pragma unroll
    for (int r = 0; r < 4; ++r) {
#pragma unroll
        for (int off = 1; off < 16; off <<= 1) {
            lA[r] += __shfl_xor(lA[r], off);
            lB[r] += __shfl_xor(lB[r], off);
        }
    }
    const int b = bh >> 4, h = bh & 15;
#pragma unroll
    for (int r = 0; r < 4; ++r) {
        const float invA = 1.f / lA[r];
        const float invB = 1.f / lB[r];
        const size_t offA = ((size_t)b * T_ + rowA + quad * 4 + r) * E_ + h * HS_;
        const size_t offB = ((size_t)b * T_ + rowB + quad * 4 + r) * E_ + h * HS_;
#pragma unroll
        for (int dt = 0; dt < 4; ++dt) {
            O[offA + dt * 16 + l15] = f2bf(oA[dt][r] * invA);
            O[offB + dt * 16 + l15] = f2bf(oB[dt][r] * invB);
        }
    }
}

// ===========================================================================
extern "C" void kernel_launch(void* const* d_in, const int* in_sizes, int n_in,
                              void* d_out, int out_size, void* d_ws, size_t ws_size,
                              hipStream_t stream) {
    // setup_inputs order: x, Wk, Wq, Wv, Wproj, i  (all float32)
    const float* x  = (const float*)d_in[0];
    const float* Wk = (const float*)d_in[1];
    const float* Wq = (const float*)d_in[2];
    const float* Wv = (const float*)d_in[3];
    const float* Wp = (const float*)d_in[4];

    const size_t qe = (size_t)B_ * H_ * T_ * HS_;   // 8,388,608 elems
    const size_t we = (size_t)E_ * E_;              // 1,048,576 elems

    // ws: xb(16M, reused as o) | wq | wk | wv | wp | q | k | vT  (~76 MB)
    us* xb = (us*)d_ws;
    us* wq = xb + qe;
    us* wk = wq + we;
    us* wv = wk + we;
    us* wp = wv + we;
    us* q  = wp + we;
    us* k  = q + qe;
    us* vT = k + qe;
    us* o  = xb;   // xb dead after qkv_gf

    cvt_kernel<<<dim3(4096, 5), 256, 0, stream>>>(x, Wq, Wk, Wv, Wp,
                                                  xb, wq, wk, wv, wp);
    qkv_gf<<<dim3(64, 8, 3), 256, 0, stream>>>(xb, wq, wk, wv, q, k, vT);
    attn_v8<<<dim3(8, 128), 256, 0, stream>>>(q, k, vT, o);
    proj_gf<<<dim3(64, 8), 256, 0, stream>>>(o, wp, (float*)d_out);
}